// Round 16
// baseline (42.760 us; speedup 1.0000x reference)
//
#include <hip/hip_runtime.h>
#include <math.h>

#define N_SPK 1024
#define M_UTT 32
#define M_ENR 16
#define M_TEST 16
#define D 512
#define N_TEST_ROWS (N_SPK * M_TEST)   // 16384

// gemm: 8-phase counted-vmcnt schedule, tile 256spk x 256test, BK=64,
// 8 waves (2M x 4N), wave tile 128spk x 64test. NEW: MFMA shape 32x32x16
// (µbench 2382-2495 TF vs 2075-2176 for 16x16; 4x fewer instructions).
// Swapped operands mfma(bf, af): D rows = test, D cols = speaker.
// acc = f32x16[4 spk-tiles][2 test-tiles] = 128 regs (same as R15).
// Staging/swizzle/vmcnt/phase graph identical to the verified R14/R15 kernel.

typedef __attribute__((ext_vector_type(4))) float f32x4;
typedef __attribute__((ext_vector_type(16))) float f32x16;
typedef __attribute__((ext_vector_type(8))) short short8;
typedef __attribute__((ext_vector_type(8))) unsigned short ushort8;

typedef const __attribute__((address_space(1))) void g_void;
typedef __attribute__((address_space(3))) void lds_void;

__device__ __forceinline__ unsigned short f2bf(float f) {
    unsigned int u = __float_as_uint(f);
    u += 0x7FFF + ((u >> 16) & 1);   // round-to-nearest-even
    return (unsigned short)(u >> 16);
}

// ---------------------------------------------------------------------------
// Kernel 1: centroids (float2 loads) + test-row normalize; blocks [0,4) zero
// g_row/g_pos. (R15-verbatim)
// ---------------------------------------------------------------------------
__global__ __launch_bounds__(256) void prep_kernel(const float* __restrict__ emb,
                                                   unsigned short* __restrict__ cent,
                                                   unsigned short* __restrict__ test,
                                                   float* __restrict__ g_row,
                                                   float* __restrict__ g_pos) {
    const int b = blockIdx.x;
    const int tid = threadIdx.x;
    const int lane = tid & 63;
    const int wid = tid >> 6;

    if (b < 4) {
        g_row[b * 256 + tid] = 0.f;
        g_pos[b * 256 + tid] = 0.f;
    }

    if (b < N_SPK) {
        const float2* base2 = (const float2*)(emb + (size_t)b * M_UTT * D);
        float a0 = 0.f, a1 = 0.f;
#pragma unroll
        for (int u = 0; u < M_ENR; ++u) {
            const float2 v = base2[u * 256 + tid];   // cols 2tid, 2tid+1
            a0 += v.x; a1 += v.y;
        }
        a0 *= (1.f / 16.f);
        a1 *= (1.f / 16.f);
        float ss = a0 * a0 + a1 * a1;
#pragma unroll
        for (int m = 1; m < 64; m <<= 1) ss += __shfl_xor(ss, m, 64);
        __shared__ float wss[4];
        if (lane == 0) wss[wid] = ss;
        __syncthreads();
        const float tot = wss[0] + wss[1] + wss[2] + wss[3];
        const float inv = 1.f / fmaxf(sqrtf(tot), 1e-8f);
        ushort2 o2;
        o2.x = f2bf(a0 * inv);
        o2.y = f2bf(a1 * inv);
        *(ushort2*)&cent[b * D + 2 * tid] = o2;
    } else {
        const int r = (b - N_SPK) * 4 + wid;   // test row 0..16383
        const int s = r >> 4, t = r & 15;
        const float* row = emb + ((size_t)s * M_UTT + M_ENR + t) * D;
        const f32x4* rv = (const f32x4*)row;
        const f32x4 v0 = rv[lane * 2];
        const f32x4 v1 = rv[lane * 2 + 1];
        float ss = v0[0]*v0[0] + v0[1]*v0[1] + v0[2]*v0[2] + v0[3]*v0[3]
                 + v1[0]*v1[0] + v1[1]*v1[1] + v1[2]*v1[2] + v1[3]*v1[3];
#pragma unroll
        for (int m = 1; m < 64; m <<= 1) ss += __shfl_xor(ss, m, 64);
        const float inv = 1.f / fmaxf(sqrtf(ss), 1e-8f);
        ushort8 o;
        o[0] = f2bf(v0[0] * inv); o[1] = f2bf(v0[1] * inv);
        o[2] = f2bf(v0[2] * inv); o[3] = f2bf(v0[3] * inv);
        o[4] = f2bf(v1[0] * inv); o[5] = f2bf(v1[1] * inv);
        o[6] = f2bf(v1[2] * inv); o[7] = f2bf(v1[3] * inv);
        *(ushort8*)&test[(size_t)r * D + lane * 8] = o;
    }
}

// ---------------------------------------------------------------------------
// Kernel 2: 8-phase GEMM, 32x32x16 MFMA, swapped-operand epilogue.
// ---------------------------------------------------------------------------
__global__ __launch_bounds__(512) void gemm_kernel(const unsigned short* __restrict__ A,  // cent 1024x512
                                                   const unsigned short* __restrict__ B,  // test 16384x512
                                                   const float* __restrict__ alpha_p,
                                                   const float* __restrict__ beta_p,
                                                   float* __restrict__ g_row,
                                                   float* __restrict__ g_pos) {
    __shared__ __align__(16) unsigned short AsL[2 * 256 * 64];   // 64 KB
    __shared__ __align__(16) unsigned short BsL[2 * 256 * 64];   // 64 KB
    __shared__ float rowsum[256];
    __shared__ float possum[256];

    const int tid = threadIdx.x;
    const int lane = tid & 63;
    const int w = tid >> 6;          // wave 0..7
    const int wr = w >> 2;           // 0..1  M-half (128 speaker rows)
    const int wc = w & 3;            // 0..3  N-quarter (64 test cols)
    const int l31 = lane & 31;

    // XCD swizzle: 256 blocks = 8 XCDs x 32 -> each XCD: 8 bj panels (2 MB B) + A.
    const int raw = blockIdx.x;
    const int wg = (raw & 7) * 32 + (raw >> 3);
    const int bi = wg & 3;           // 4 speaker panels (256 rows)
    const int bj = wg >> 2;          // 64 test panels (256 cols)
    const int row0 = bi * 256, col0 = bj * 256;
    const bool has_diag = ((bj >> 4) == bi);

    // staging swizzle (R14-verbatim): LDS[row][slot s] = G[row][s ^ (row&7)]
    const int sw8 = 8 * ((lane & 7) ^ (lane >> 3));
    // 32-row fragment read: row = base + l31 (row&7 = lane&7); global elem
    // ofs wanted = k*16 + (lane>>5)*8  ->  LDS ofs = (k*16) ^ hs32
    const int hs32 = ((lane >> 5) * 8) ^ ((lane & 7) << 3);

    const float alpha = *alpha_p;
    const float beta = *beta_p;

#define STAGE_H(OP, BUF, HF, KT)                                               \
    {                                                                          \
        const unsigned short* gb_ = (OP) ? B : A;                              \
        const int r0_ = ((OP) ? col0 : row0) + (HF) * 128;                     \
        _Pragma("unroll") for (int i_ = 0; i_ < 2; ++i_) {                     \
            const int rl_ = i_ * 64 + w * 8 + (lane >> 3);                     \
            unsigned short* lb_ = ((OP) ? BsL : AsL) +                         \
                (BUF) * 16384 + ((HF) * 128 + i_ * 64 + w * 8) * 64;           \
            __builtin_amdgcn_global_load_lds(                                  \
                (g_void*)&gb_[(size_t)(r0_ + rl_) * D + (KT) * 64 + sw8],      \
                (lds_void*)lb_, 16, 0, 0);                                     \
        }                                                                      \
    }

    // A (speaker) fragments: MIH selects spk-tile pair {0,1} or {2,3}.
    // af[j*4+k] = A-frag for spk tile (MIH*2+j), K-step k (K=16 each).
#define LDA8(BUF, MIH)                                                         \
    _Pragma("unroll") for (int j_ = 0; j_ < 2; ++j_) {                         \
        const int row_ = wr * 128 + ((MIH) * 2 + j_) * 32 + l31;               \
        _Pragma("unroll") for (int k_ = 0; k_ < 4; ++k_)                       \
            af[j_ * 4 + k_] = *(const short8*)                                 \
                &AsL[(BUF) * 16384 + row_ * 64 + ((k_ * 16) ^ hs32)];          \
    }
    // B (test) fragments: NIH selects test tile 0 or 1; DST[k] per K-step.
#define LDB4(DST, BUF, NIH)                                                    \
    {                                                                          \
        const int row_ = wc * 64 + (NIH) * 32 + l31;                           \
        _Pragma("unroll") for (int k_ = 0; k_ < 4; ++k_)                       \
            DST[k_] = *(const short8*)                                         \
                &BsL[(BUF) * 16384 + row_ * 64 + ((k_ * 16) ^ hs32)];          \
    }

    // Swapped operands: D = bf x af -> D rows = test, D cols = speaker.
    // acc[spk_tile 0..3][test_tile 0..1], f32x16 each.
#define MM(BF, MIH, NIH)                                                       \
    {                                                                          \
        __builtin_amdgcn_s_setprio(1);                                         \
        _Pragma("unroll") for (int j_ = 0; j_ < 2; ++j_)                       \
            _Pragma("unroll") for (int k_ = 0; k_ < 4; ++k_)                   \
                acc[(MIH) * 2 + j_][(NIH)] =                                   \
                    __builtin_amdgcn_mfma_f32_32x32x16_bf16(                   \
                        BF[k_], af[j_ * 4 + k_], acc[(MIH) * 2 + j_][(NIH)],   \
                        0, 0, 0);                                              \
        __builtin_amdgcn_s_setprio(0);                                         \
    }

#define VM4 asm volatile("s_waitcnt vmcnt(4)" ::: "memory")
#define VM0 asm volatile("s_waitcnt vmcnt(0)" ::: "memory")
#define BAR __builtin_amdgcn_s_barrier()

    f32x16 acc[4][2] = {};
    short8 af[8], bf0[4], bf1[4];

    // ---- prologue: T0 full + T1-B; confirm T0. (R14-verbatim)
    STAGE_H(0, 0, 0, 0) STAGE_H(0, 0, 1, 0) STAGE_H(1, 0, 0, 0) STAGE_H(1, 0, 1, 0)
    STAGE_H(1, 1, 0, 1) STAGE_H(1, 1, 1, 1)
    if (tid < 256) { rowsum[tid] = 0.f; possum[tid] = 0.f; }
    VM4;
    BAR;

    // ---- main loop: 4 iterations x 8 phases, 2 K-tiles each. (R14-verbatim)
#pragma unroll
    for (int it = 0; it < 4; ++it) {
        LDA8(0, 0) LDB4(bf0, 0, 0)
        STAGE_H(0, 1, 0, 2 * it + 1)
        BAR; MM(bf0, 0, 0) BAR;

        LDB4(bf1, 0, 1)
        STAGE_H(0, 1, 1, 2 * it + 1)
        BAR; MM(bf1, 0, 1) BAR;

        LDA8(0, 1)
        if (it < 3) STAGE_H(1, 0, 0, 2 * it + 2)
        BAR; MM(bf1, 1, 1) BAR;

        if (it < 3) { STAGE_H(1, 0, 1, 2 * it + 2) VM4; } else { VM0; }
        BAR; MM(bf0, 1, 0) BAR;

        LDA8(1, 0) LDB4(bf0, 1, 0)
        if (it < 3) STAGE_H(0, 0, 0, 2 * it + 2)
        BAR; MM(bf0, 0, 0) BAR;

        LDB4(bf1, 1, 1)
        if (it < 3) STAGE_H(0, 0, 1, 2 * it + 2)
        BAR; MM(bf1, 0, 1) BAR;

        LDA8(1, 1)
        if (it < 3) STAGE_H(1, 1, 0, 2 * it + 3)
        BAR; MM(bf1, 1, 1) BAR;

        if (it < 3) { STAGE_H(1, 1, 1, 2 * it + 3) VM4; }
        BAR; MM(bf0, 1, 0) BAR;
    }
#undef STAGE_H
#undef LDA8
#undef LDB4
#undef MM
#undef VM4
#undef VM0
#undef BAR

    // ---- epilogue: e = exp(alpha*s + beta); per-speaker sums.
    // 32x32 C/D layout [m74/m101]: col = lane&31 (= speaker),
    // row = (r&3) + 8*(r>>2) + 4*(lane>>5) (= test row within tile).
    const int bcol = col0 + wc * 64;
    const int h4 = (lane >> 5) << 2;
#pragma unroll
    for (int st = 0; st < 4; ++st) {
        const int lspk = wr * 128 + st * 32 + l31;     // local speaker
        const int gs = row0 + lspk;                    // global speaker
        float t = 0.f, p = 0.f;
#pragma unroll
        for (int tt = 0; tt < 2; ++tt) {
#pragma unroll
            for (int r = 0; r < 16; ++r) {
                const float e = __expf(fmaf(alpha, acc[st][tt][r], beta));
                t += e;
                if (has_diag) {
                    const int gt = bcol + tt * 32 + (r & 3) + 8 * (r >> 2) + h4;
                    p += ((gt >> 4) == gs) ? e : 0.f;
                }
            }
        }
        t += __shfl_xor(t, 32, 64);
        if (lane < 32) atomicAdd(&rowsum[lspk], t);
        if (has_diag) {
            p += __shfl_xor(p, 32, 64);
            if (lane < 32) atomicAdd(&possum[lspk], p);
        }
    }
    __syncthreads();
    if (tid < 256) {
        atomicAdd(&g_row[row0 + tid], rowsum[tid]);
        if (has_diag) atomicAdd(&g_pos[row0 + tid], possum[tid]);
    }
}

// ---------------------------------------------------------------------------
// Kernel 3: loss = mean(log(tot - pos) - log(pos)) — shfl-based, 1 barrier.
// ---------------------------------------------------------------------------
__global__ __launch_bounds__(1024) void finalize_kernel(const float* __restrict__ g_row,
                                                        const float* __restrict__ g_pos,
                                                        float* __restrict__ out) {
    __shared__ float wsum[16];
    const int i = threadIdx.x;
    const int lane = i & 63, wid = i >> 6;
    const float pos = g_pos[i];
    const float neg = g_row[i] - pos;
    float v = logf(fmaxf(neg, 1e-30f)) - logf(fmaxf(pos, 1e-30f));
#pragma unroll
    for (int m = 1; m < 64; m <<= 1) v += __shfl_xor(v, m, 64);
    if (lane == 0) wsum[wid] = v;
    __syncthreads();
    if (i < 64) {
        float s = (i < 16) ? wsum[i] : 0.f;
#pragma unroll
        for (int m = 1; m < 16; m <<= 1) s += __shfl_xor(s, m, 64);
        if (i == 0) out[0] = s * (1.f / 1024.f);
    }
}

extern "C" void kernel_launch(void* const* d_in, const int* in_sizes, int n_in,
                              void* d_out, int out_size, void* d_ws, size_t ws_size,
                              hipStream_t stream) {
    const float* emb = (const float*)d_in[0];
    // d_in[1] = labels (unused; structure fixed by construction)
    const float* alpha_p = (const float*)d_in[2];
    const float* beta_p = (const float*)d_in[3];

    unsigned short* cent = (unsigned short*)d_ws;          // 1024*512 bf16 = 1 MB
    unsigned short* test = cent + (size_t)N_SPK * D;       // 16384*512 bf16 = 16 MB
    float* g_row = (float*)(test + (size_t)N_TEST_ROWS * D);
    float* g_pos = g_row + N_SPK;

    prep_kernel<<<N_SPK + N_TEST_ROWS / 4, 256, 0, stream>>>(emb, cent, test, g_row, g_pos);

    gemm_kernel<<<256, 512, 0, stream>>>(cent, test, alpha_p, beta_p, g_row, g_pos);

    finalize_kernel<<<1, 1024, 0, stream>>>(g_row, g_pos, (float*)d_out);
}

// Round 17
// 40.593 us; speedup vs baseline: 1.0534x; 1.0534x over previous
//
#include <hip/hip_runtime.h>
#include <math.h>

#define N_SPK 1024
#define M_UTT 32
#define M_ENR 16
#define M_TEST 16
#define D 512
#define N_TEST_ROWS (N_SPK * M_TEST)   // 16384

// FINAL (revert to R15, measured 40.5 us total, absmax 0.0):
// gemm: 8-phase counted-vmcnt schedule (T3+T4+T2+T5), tile 256spk x 256test,
// BK=64 (8 K-tiles, 2/iter), 8 waves (2M x 4N), wave tile 128x64
// (acc[8][4] = 128 AGPR). LDS dbuf A/B K-tiles (128 KB), XOR-swizzled via
// pre-swizzled global source. Loads in flight ACROSS raw s_barriers;
// vmcnt(4) gates at phases 4/8 only. 2 waves/SIMD. MFMA operands swapped
// (mfma(bf,af) = D-transpose): speaker axis on lane&15 -> per-speaker
// reduction = 16 VALU adds + 2 shuffles per mi. 16x16x32 shape (R16 showed
// 32x32x16 loses via dependent-accumulator chains). prep: float2 centroid
// loads + ushort8 test writes; separate tiny finalize (fusion regresses).

typedef __attribute__((ext_vector_type(4))) float f32x4;
typedef __attribute__((ext_vector_type(8))) short short8;
typedef __attribute__((ext_vector_type(8))) unsigned short ushort8;

typedef const __attribute__((address_space(1))) void g_void;
typedef __attribute__((address_space(3))) void lds_void;

__device__ __forceinline__ unsigned short f2bf(float f) {
    unsigned int u = __float_as_uint(f);
    u += 0x7FFF + ((u >> 16) & 1);   // round-to-nearest-even
    return (unsigned short)(u >> 16);
}

// ---------------------------------------------------------------------------
// Kernel 1: centroids (float2 loads) + test-row normalize; blocks [0,4) zero
// g_row/g_pos.
// ---------------------------------------------------------------------------
__global__ __launch_bounds__(256) void prep_kernel(const float* __restrict__ emb,
                                                   unsigned short* __restrict__ cent,
                                                   unsigned short* __restrict__ test,
                                                   float* __restrict__ g_row,
                                                   float* __restrict__ g_pos) {
    const int b = blockIdx.x;
    const int tid = threadIdx.x;
    const int lane = tid & 63;
    const int wid = tid >> 6;

    if (b < 4) {
        g_row[b * 256 + tid] = 0.f;
        g_pos[b * 256 + tid] = 0.f;
    }

    if (b < N_SPK) {
        const float2* base2 = (const float2*)(emb + (size_t)b * M_UTT * D);
        float a0 = 0.f, a1 = 0.f;
#pragma unroll
        for (int u = 0; u < M_ENR; ++u) {
            const float2 v = base2[u * 256 + tid];   // cols 2tid, 2tid+1
            a0 += v.x; a1 += v.y;
        }
        a0 *= (1.f / 16.f);
        a1 *= (1.f / 16.f);
        float ss = a0 * a0 + a1 * a1;
#pragma unroll
        for (int m = 1; m < 64; m <<= 1) ss += __shfl_xor(ss, m, 64);
        __shared__ float wss[4];
        if (lane == 0) wss[wid] = ss;
        __syncthreads();
        const float tot = wss[0] + wss[1] + wss[2] + wss[3];
        const float inv = 1.f / fmaxf(sqrtf(tot), 1e-8f);
        ushort2 o2;
        o2.x = f2bf(a0 * inv);
        o2.y = f2bf(a1 * inv);
        *(ushort2*)&cent[b * D + 2 * tid] = o2;
    } else {
        const int r = (b - N_SPK) * 4 + wid;   // test row 0..16383
        const int s = r >> 4, t = r & 15;
        const float* row = emb + ((size_t)s * M_UTT + M_ENR + t) * D;
        const f32x4* rv = (const f32x4*)row;
        const f32x4 v0 = rv[lane * 2];
        const f32x4 v1 = rv[lane * 2 + 1];
        float ss = v0[0]*v0[0] + v0[1]*v0[1] + v0[2]*v0[2] + v0[3]*v0[3]
                 + v1[0]*v1[0] + v1[1]*v1[1] + v1[2]*v1[2] + v1[3]*v1[3];
#pragma unroll
        for (int m = 1; m < 64; m <<= 1) ss += __shfl_xor(ss, m, 64);
        const float inv = 1.f / fmaxf(sqrtf(ss), 1e-8f);
        ushort8 o;
        o[0] = f2bf(v0[0] * inv); o[1] = f2bf(v0[1] * inv);
        o[2] = f2bf(v0[2] * inv); o[3] = f2bf(v0[3] * inv);
        o[4] = f2bf(v1[0] * inv); o[5] = f2bf(v1[1] * inv);
        o[6] = f2bf(v1[2] * inv); o[7] = f2bf(v1[3] * inv);
        *(ushort8*)&test[(size_t)r * D + lane * 8] = o;
    }
}

// ---------------------------------------------------------------------------
// Kernel 2: 8-phase GEMM, swapped-operand epilogue.
// ---------------------------------------------------------------------------
__global__ __launch_bounds__(512) void gemm_kernel(const unsigned short* __restrict__ A,  // cent 1024x512
                                                   const unsigned short* __restrict__ B,  // test 16384x512
                                                   const float* __restrict__ alpha_p,
                                                   const float* __restrict__ beta_p,
                                                   float* __restrict__ g_row,
                                                   float* __restrict__ g_pos) {
    __shared__ __align__(16) unsigned short AsL[2 * 256 * 64];   // 64 KB
    __shared__ __align__(16) unsigned short BsL[2 * 256 * 64];   // 64 KB
    __shared__ float rowsum[256];
    __shared__ float possum[256];

    const int tid = threadIdx.x;
    const int lane = tid & 63;
    const int w = tid >> 6;          // wave 0..7
    const int wr = w >> 2;           // 0..1  M-half (128 speaker rows)
    const int wc = w & 3;            // 0..3  N-quarter (64 test cols)
    const int l15 = lane & 15;

    // XCD swizzle: 256 blocks = 8 XCDs x 32 -> each XCD: 8 bj panels (2 MB B) + A.
    const int raw = blockIdx.x;
    const int wg = (raw & 7) * 32 + (raw >> 3);
    const int bi = wg & 3;           // 4 speaker panels (256 rows)
    const int bj = wg >> 2;          // 64 test panels (256 cols)
    const int row0 = bi * 256, col0 = bj * 256;
    const bool has_diag = ((bj >> 4) == bi);

    // staging swizzle: LDS[row][slot s] = global slot s ^ (row&7), 16B slots
    const int sw8 = 8 * ((lane & 7) ^ (lane >> 3));   // source elem offset
    // read swizzle: elem ofs = (kk + (lane>>4)*8) ^ ((lane&7)<<3) = kk ^ hs
    const int hs = ((lane >> 4) * 8) ^ ((lane & 7) << 3);

    const float alpha = *alpha_p;
    const float beta = *beta_p;

#define STAGE_H(OP, BUF, HF, KT)                                               \
    {                                                                          \
        const unsigned short* gb_ = (OP) ? B : A;                              \
        const int r0_ = ((OP) ? col0 : row0) + (HF) * 128;                     \
        _Pragma("unroll") for (int i_ = 0; i_ < 2; ++i_) {                     \
            const int rl_ = i_ * 64 + w * 8 + (lane >> 3);                     \
            unsigned short* lb_ = ((OP) ? BsL : AsL) +                         \
                (BUF) * 16384 + ((HF) * 128 + i_ * 64 + w * 8) * 64;           \
            __builtin_amdgcn_global_load_lds(                                  \
                (g_void*)&gb_[(size_t)(r0_ + rl_) * D + (KT) * 64 + sw8],      \
                (lds_void*)lb_, 16, 0, 0);                                     \
        }                                                                      \
    }

#define LDA8(BUF, MIH)                                                         \
    _Pragma("unroll") for (int j_ = 0; j_ < 4; ++j_) {                         \
        const int row_ = wr * 128 + ((MIH) * 4 + j_) * 16 + l15;               \
        af[j_ * 2]     = *(const short8*)&AsL[(BUF) * 16384 + row_ * 64 + (0 ^ hs)];  \
        af[j_ * 2 + 1] = *(const short8*)&AsL[(BUF) * 16384 + row_ * 64 + (32 ^ hs)]; \
    }
#define LDB4(DST, BUF, NIH)                                                    \
    _Pragma("unroll") for (int n_ = 0; n_ < 2; ++n_) {                         \
        const int row_ = wc * 64 + ((NIH) * 2 + n_) * 16 + l15;                \
        DST[n_ * 2]     = *(const short8*)&BsL[(BUF) * 16384 + row_ * 64 + (0 ^ hs)];  \
        DST[n_ * 2 + 1] = *(const short8*)&BsL[(BUF) * 16384 + row_ * 64 + (32 ^ hs)]; \
    }

    // SWAPPED operands: D' = D^T. acc[mi][ni]: col(lane&15) = speaker
    // (row0 + wr*128 + mi*16 + l15), row((lane>>4)*4+r) = test
    // (col0 + wc*64 + ni*16 + (lane>>4)*4 + r).
#define MM(BF, MIH, NIH)                                                       \
    {                                                                          \
        __builtin_amdgcn_s_setprio(1);                                         \
        _Pragma("unroll") for (int j_ = 0; j_ < 4; ++j_)                       \
            _Pragma("unroll") for (int n_ = 0; n_ < 2; ++n_)                   \
                _Pragma("unroll") for (int k_ = 0; k_ < 2; ++k_)               \
                    acc[(MIH) * 4 + j_][(NIH) * 2 + n_] =                      \
                        __builtin_amdgcn_mfma_f32_16x16x32_bf16(               \
                            BF[n_ * 2 + k_], af[j_ * 2 + k_],                  \
                            acc[(MIH) * 4 + j_][(NIH) * 2 + n_], 0, 0, 0);     \
        __builtin_amdgcn_s_setprio(0);                                         \
    }

#define VM4 asm volatile("s_waitcnt vmcnt(4)" ::: "memory")
#define VM0 asm volatile("s_waitcnt vmcnt(0)" ::: "memory")
#define BAR __builtin_amdgcn_s_barrier()

    f32x4 acc[8][4] = {};
    short8 af[8], bf0[4], bf1[4];

    // ---- prologue: T0 full (4 halves) + T1-B (2 halves); confirm T0.
    STAGE_H(0, 0, 0, 0) STAGE_H(0, 0, 1, 0) STAGE_H(1, 0, 0, 0) STAGE_H(1, 0, 1, 0)
    STAGE_H(1, 1, 0, 1) STAGE_H(1, 1, 1, 1)
    if (tid < 256) { rowsum[tid] = 0.f; possum[tid] = 0.f; }
    VM4;                       // T0's 8 loads landed; T1-B (4) in flight
    BAR;

    // ---- main loop: 4 iterations x 8 phases, 2 K-tiles each.
#pragma unroll
    for (int it = 0; it < 4; ++it) {
        LDA8(0, 0) LDB4(bf0, 0, 0)
        STAGE_H(0, 1, 0, 2 * it + 1)
        BAR; MM(bf0, 0, 0) BAR;

        LDB4(bf1, 0, 1)
        STAGE_H(0, 1, 1, 2 * it + 1)
        BAR; MM(bf1, 0, 1) BAR;

        LDA8(0, 1)
        if (it < 3) STAGE_H(1, 0, 0, 2 * it + 2)
        BAR; MM(bf1, 1, 1) BAR;

        if (it < 3) { STAGE_H(1, 0, 1, 2 * it + 2) VM4; } else { VM0; }
        BAR; MM(bf0, 1, 0) BAR;

        LDA8(1, 0) LDB4(bf0, 1, 0)
        if (it < 3) STAGE_H(0, 0, 0, 2 * it + 2)
        BAR; MM(bf0, 0, 0) BAR;

        LDB4(bf1, 1, 1)
        if (it < 3) STAGE_H(0, 0, 1, 2 * it + 2)
        BAR; MM(bf1, 0, 1) BAR;

        LDA8(1, 1)
        if (it < 3) STAGE_H(1, 1, 0, 2 * it + 3)
        BAR; MM(bf1, 1, 1) BAR;

        if (it < 3) { STAGE_H(1, 1, 1, 2 * it + 3) VM4; }
        BAR; MM(bf0, 1, 0) BAR;
    }
#undef STAGE_H
#undef LDA8
#undef LDB4
#undef MM
#undef VM4
#undef VM0
#undef BAR

    // ---- epilogue (swapped layout): per-speaker sum = 16 VALU adds over
    // (ni,r) + 2 shuffles over lane>>4; speaker = lane&15 within mi-group.
    const int bcol = col0 + wc * 64;
    const int k4 = (lane >> 4) << 2;
#pragma unroll
    for (int mi = 0; mi < 8; ++mi) {
        const int lspk = wr * 128 + mi * 16 + l15;     // local speaker row
        const int gs = row0 + lspk;                    // global speaker
        float t = 0.f, p = 0.f;
#pragma unroll
        for (int ni = 0; ni < 4; ++ni) {
#pragma unroll
            for (int r = 0; r < 4; ++r) {
                const float e = __expf(fmaf(alpha, acc[mi][ni][r], beta));
                t += e;
                if (has_diag) {
                    const int gt = bcol + ni * 16 + k4 + r;   // global test row
                    p += ((gt >> 4) == gs) ? e : 0.f;
                }
            }
        }
        t += __shfl_xor(t, 16, 64);
        t += __shfl_xor(t, 32, 64);
        if (lane < 16) atomicAdd(&rowsum[lspk], t);
        if (has_diag) {
            p += __shfl_xor(p, 16, 64);
            p += __shfl_xor(p, 32, 64);
            if (lane < 16) atomicAdd(&possum[lspk], p);
        }
    }
    __syncthreads();
    if (tid < 256) {
        atomicAdd(&g_row[row0 + tid], rowsum[tid]);
        if (has_diag) atomicAdd(&g_pos[row0 + tid], possum[tid]);
    }
}

// ---------------------------------------------------------------------------
// Kernel 3: loss = mean(log(tot - pos) - log(pos)) — shfl-based, 1 barrier.
// ---------------------------------------------------------------------------
__global__ __launch_bounds__(1024) void finalize_kernel(const float* __restrict__ g_row,
                                                        const float* __restrict__ g_pos,
                                                        float* __restrict__ out) {
    __shared__ float wsum[16];
    const int i = threadIdx.x;
    const int lane = i & 63, wid = i >> 6;
    const float pos = g_pos[i];
    const float neg = g_row[i] - pos;
    float v = logf(fmaxf(neg, 1e-30f)) - logf(fmaxf(pos, 1e-30f));
#pragma unroll
    for (int m = 1; m < 64; m <<= 1) v += __shfl_xor(v, m, 64);
    if (lane == 0) wsum[wid] = v;
    __syncthreads();
    if (i < 64) {
        float s = (i < 16) ? wsum[i] : 0.f;
#pragma unroll
        for (int m = 1; m < 16; m <<= 1) s += __shfl_xor(s, m, 64);
        if (i == 0) out[0] = s * (1.f / 1024.f);
    }
}

extern "C" void kernel_launch(void* const* d_in, const int* in_sizes, int n_in,
                              void* d_out, int out_size, void* d_ws, size_t ws_size,
                              hipStream_t stream) {
    const float* emb = (const float*)d_in[0];
    // d_in[1] = labels (unused; structure fixed by construction)
    const float* alpha_p = (const float*)d_in[2];
    const float* beta_p = (const float*)d_in[3];

    unsigned short* cent = (unsigned short*)d_ws;          // 1024*512 bf16 = 1 MB
    unsigned short* test = cent + (size_t)N_SPK * D;       // 16384*512 bf16 = 16 MB
    float* g_row = (float*)(test + (size_t)N_TEST_ROWS * D);
    float* g_pos = g_row + N_SPK;

    prep_kernel<<<N_SPK + N_TEST_ROWS / 4, 256, 0, stream>>>(emb, cent, test, g_row, g_pos);

    gemm_kernel<<<256, 512, 0, stream>>>(cent, test, alpha_p, beta_p, g_row, g_pos);

    finalize_kernel<<<1, 1024, 0, stream>>>(g_row, g_pos, (float*)d_out);
}

// Round 18
// 40.255 us; speedup vs baseline: 1.0622x; 1.0084x over previous
//
#include <hip/hip_runtime.h>
#include <math.h>

#define N_SPK 1024
#define M_UTT 32
#define M_ENR 16
#define M_TEST 16
#define D 512
#define N_TEST_ROWS (N_SPK * M_TEST)   // 16384

// gemm: 4-phase counted-vmcnt schedule (merged from the verified 8-phase
// R15/R17 kernel: B1-only phases folded into predecessors -> 32 barriers
// instead of 64; ds_read/MFMA/stage totals and vmcnt gates IDENTICAL).
// tile 256spk x 256test, BK=64 (8 K-tiles, 2/iter), 8 waves (2M x 4N),
// wave tile 128x64 (acc[8][4] = 128 AGPR). LDS dbuf A/B K-tiles (128 KB),
// XOR-swizzled via pre-swizzled global source. Loads in flight ACROSS raw
// s_barriers; vmcnt(4) gates at P2/P4 only. Swapped operands mfma(bf,af).

typedef __attribute__((ext_vector_type(4))) float f32x4;
typedef __attribute__((ext_vector_type(8))) short short8;
typedef __attribute__((ext_vector_type(8))) unsigned short ushort8;

typedef const __attribute__((address_space(1))) void g_void;
typedef __attribute__((address_space(3))) void lds_void;

__device__ __forceinline__ unsigned short f2bf(float f) {
    unsigned int u = __float_as_uint(f);
    u += 0x7FFF + ((u >> 16) & 1);   // round-to-nearest-even
    return (unsigned short)(u >> 16);
}

// ---------------------------------------------------------------------------
// Kernel 1: centroids (float2 loads) + test-row normalize; blocks [0,4) zero
// g_row/g_pos. (R15-verbatim)
// ---------------------------------------------------------------------------
__global__ __launch_bounds__(256) void prep_kernel(const float* __restrict__ emb,
                                                   unsigned short* __restrict__ cent,
                                                   unsigned short* __restrict__ test,
                                                   float* __restrict__ g_row,
                                                   float* __restrict__ g_pos) {
    const int b = blockIdx.x;
    const int tid = threadIdx.x;
    const int lane = tid & 63;
    const int wid = tid >> 6;

    if (b < 4) {
        g_row[b * 256 + tid] = 0.f;
        g_pos[b * 256 + tid] = 0.f;
    }

    if (b < N_SPK) {
        const float2* base2 = (const float2*)(emb + (size_t)b * M_UTT * D);
        float a0 = 0.f, a1 = 0.f;
#pragma unroll
        for (int u = 0; u < M_ENR; ++u) {
            const float2 v = base2[u * 256 + tid];   // cols 2tid, 2tid+1
            a0 += v.x; a1 += v.y;
        }
        a0 *= (1.f / 16.f);
        a1 *= (1.f / 16.f);
        float ss = a0 * a0 + a1 * a1;
#pragma unroll
        for (int m = 1; m < 64; m <<= 1) ss += __shfl_xor(ss, m, 64);
        __shared__ float wss[4];
        if (lane == 0) wss[wid] = ss;
        __syncthreads();
        const float tot = wss[0] + wss[1] + wss[2] + wss[3];
        const float inv = 1.f / fmaxf(sqrtf(tot), 1e-8f);
        ushort2 o2;
        o2.x = f2bf(a0 * inv);
        o2.y = f2bf(a1 * inv);
        *(ushort2*)&cent[b * D + 2 * tid] = o2;
    } else {
        const int r = (b - N_SPK) * 4 + wid;   // test row 0..16383
        const int s = r >> 4, t = r & 15;
        const float* row = emb + ((size_t)s * M_UTT + M_ENR + t) * D;
        const f32x4* rv = (const f32x4*)row;
        const f32x4 v0 = rv[lane * 2];
        const f32x4 v1 = rv[lane * 2 + 1];
        float ss = v0[0]*v0[0] + v0[1]*v0[1] + v0[2]*v0[2] + v0[3]*v0[3]
                 + v1[0]*v1[0] + v1[1]*v1[1] + v1[2]*v1[2] + v1[3]*v1[3];
#pragma unroll
        for (int m = 1; m < 64; m <<= 1) ss += __shfl_xor(ss, m, 64);
        const float inv = 1.f / fmaxf(sqrtf(ss), 1e-8f);
        ushort8 o;
        o[0] = f2bf(v0[0] * inv); o[1] = f2bf(v0[1] * inv);
        o[2] = f2bf(v0[2] * inv); o[3] = f2bf(v0[3] * inv);
        o[4] = f2bf(v1[0] * inv); o[5] = f2bf(v1[1] * inv);
        o[6] = f2bf(v1[2] * inv); o[7] = f2bf(v1[3] * inv);
        *(ushort8*)&test[(size_t)r * D + lane * 8] = o;
    }
}

// ---------------------------------------------------------------------------
// Kernel 2: 4-phase GEMM, swapped-operand epilogue.
// ---------------------------------------------------------------------------
__global__ __launch_bounds__(512) void gemm_kernel(const unsigned short* __restrict__ A,  // cent 1024x512
                                                   const unsigned short* __restrict__ B,  // test 16384x512
                                                   const float* __restrict__ alpha_p,
                                                   const float* __restrict__ beta_p,
                                                   float* __restrict__ g_row,
                                                   float* __restrict__ g_pos) {
    __shared__ __align__(16) unsigned short AsL[2 * 256 * 64];   // 64 KB
    __shared__ __align__(16) unsigned short BsL[2 * 256 * 64];   // 64 KB
    __shared__ float rowsum[256];
    __shared__ float possum[256];

    const int tid = threadIdx.x;
    const int lane = tid & 63;
    const int w = tid >> 6;          // wave 0..7
    const int wr = w >> 2;           // 0..1  M-half (128 speaker rows)
    const int wc = w & 3;            // 0..3  N-quarter (64 test cols)
    const int l15 = lane & 15;

    // XCD swizzle: 256 blocks = 8 XCDs x 32 -> each XCD: 8 bj panels (2 MB B) + A.
    const int raw = blockIdx.x;
    const int wg = (raw & 7) * 32 + (raw >> 3);
    const int bi = wg & 3;           // 4 speaker panels (256 rows)
    const int bj = wg >> 2;          // 64 test panels (256 cols)
    const int row0 = bi * 256, col0 = bj * 256;
    const bool has_diag = ((bj >> 4) == bi);

    // staging swizzle: LDS[row][slot s] = global slot s ^ (row&7), 16B slots
    const int sw8 = 8 * ((lane & 7) ^ (lane >> 3));   // source elem offset
    // read swizzle: elem ofs = (kk + (lane>>4)*8) ^ ((lane&7)<<3) = kk ^ hs
    const int hs = ((lane >> 4) * 8) ^ ((lane & 7) << 3);

    const float alpha = *alpha_p;
    const float beta = *beta_p;

#define STAGE_H(OP, BUF, HF, KT)                                               \
    {                                                                          \
        const unsigned short* gb_ = (OP) ? B : A;                              \
        const int r0_ = ((OP) ? col0 : row0) + (HF) * 128;                     \
        _Pragma("unroll") for (int i_ = 0; i_ < 2; ++i_) {                     \
            const int rl_ = i_ * 64 + w * 8 + (lane >> 3);                     \
            unsigned short* lb_ = ((OP) ? BsL : AsL) +                         \
                (BUF) * 16384 + ((HF) * 128 + i_ * 64 + w * 8) * 64;           \
            __builtin_amdgcn_global_load_lds(                                  \
                (g_void*)&gb_[(size_t)(r0_ + rl_) * D + (KT) * 64 + sw8],      \
                (lds_void*)lb_, 16, 0, 0);                                     \
        }                                                                      \
    }

#define LDA8(BUF, MIH)                                                         \
    _Pragma("unroll") for (int j_ = 0; j_ < 4; ++j_) {                         \
        const int row_ = wr * 128 + ((MIH) * 4 + j_) * 16 + l15;               \
        af[j_ * 2]     = *(const short8*)&AsL[(BUF) * 16384 + row_ * 64 + (0 ^ hs)];  \
        af[j_ * 2 + 1] = *(const short8*)&AsL[(BUF) * 16384 + row_ * 64 + (32 ^ hs)]; \
    }
#define LDB4(DST, BUF, NIH)                                                    \
    _Pragma("unroll") for (int n_ = 0; n_ < 2; ++n_) {                         \
        const int row_ = wc * 64 + ((NIH) * 2 + n_) * 16 + l15;                \
        DST[n_ * 2]     = *(const short8*)&BsL[(BUF) * 16384 + row_ * 64 + (0 ^ hs)];  \
        DST[n_ * 2 + 1] = *(const short8*)&BsL[(BUF) * 16384 + row_ * 64 + (32 ^ hs)]; \
    }

    // SWAPPED operands: D' = D^T. acc[mi][ni]: col(lane&15) = speaker
    // (row0 + wr*128 + mi*16 + l15), row((lane>>4)*4+r) = test
    // (col0 + wc*64 + ni*16 + (lane>>4)*4 + r).
#define MM(BF, MIH, NIH)                                                       \
    {                                                                          \
        __builtin_amdgcn_s_setprio(1);                                         \
        _Pragma("unroll") for (int j_ = 0; j_ < 4; ++j_)                       \
            _Pragma("unroll") for (int n_ = 0; n_ < 2; ++n_)                   \
                _Pragma("unroll") for (int k_ = 0; k_ < 2; ++k_)               \
                    acc[(MIH) * 4 + j_][(NIH) * 2 + n_] =                      \
                        __builtin_amdgcn_mfma_f32_16x16x32_bf16(               \
                            BF[n_ * 2 + k_], af[j_ * 2 + k_],                  \
                            acc[(MIH) * 4 + j_][(NIH) * 2 + n_], 0, 0, 0);     \
        __builtin_amdgcn_s_setprio(0);                                         \
    }

#define VM4 asm volatile("s_waitcnt vmcnt(4)" ::: "memory")
#define VM0 asm volatile("s_waitcnt vmcnt(0)" ::: "memory")
#define BAR __builtin_amdgcn_s_barrier()

    f32x4 acc[8][4] = {};
    short8 af[8], bf0[4], bf1[4];

    // ---- prologue: T0 full (4 halves) + T1-B (2 halves); confirm T0.
    STAGE_H(0, 0, 0, 0) STAGE_H(0, 0, 1, 0) STAGE_H(1, 0, 0, 0) STAGE_H(1, 0, 1, 0)
    STAGE_H(1, 1, 0, 1) STAGE_H(1, 1, 1, 1)
    if (tid < 256) { rowsum[tid] = 0.f; possum[tid] = 0.f; }
    VM4;                       // T0's 8 loads landed; T1-B (4) in flight
    BAR;

    // ---- main loop: 4 iterations x 4 phases, 2 K-tiles each.
    // Gate accounting (per wave, issue order):
    //  P2 gate: outstanding = B(T+1)->buf1[4] A(T+1)->buf1[4] B(T+2)->buf0[4]
    //           vmcnt(4) -> oldest 8 (= all of buf1) landed before P3.
    //  P4 gate: outstanding = A(T+2)->buf0[4] B(T+3)->buf1[4]
    //           vmcnt(4) -> buf0-A landed before next-iter P1.
#pragma unroll
    for (int it = 0; it < 4; ++it) {
        // P1: compute buf0 MIH=0 (32 MFMA); stage A(T+1)->buf1 (both halves)
        LDA8(0, 0) LDB4(bf0, 0, 0) LDB4(bf1, 0, 1)
        STAGE_H(0, 1, 0, 2 * it + 1) STAGE_H(0, 1, 1, 2 * it + 1)
        BAR; MM(bf0, 0, 0) MM(bf1, 0, 1) BAR;

        // P2: compute buf0 MIH=1; stage B(T+2)->buf0; gate buf1 readiness
        LDA8(0, 1)
        if (it < 3) { STAGE_H(1, 0, 0, 2 * it + 2) STAGE_H(1, 0, 1, 2 * it + 2) VM4; }
        else { VM0; }
        BAR; MM(bf1, 1, 1) MM(bf0, 1, 0) BAR;

        // P3: compute buf1 MIH=0; stage A(T+2)->buf0
        LDA8(1, 0) LDB4(bf0, 1, 0) LDB4(bf1, 1, 1)
        if (it < 3) { STAGE_H(0, 0, 0, 2 * it + 2) STAGE_H(0, 0, 1, 2 * it + 2) }
        BAR; MM(bf0, 0, 0) MM(bf1, 0, 1) BAR;

        // P4: compute buf1 MIH=1; stage B(T+3)->buf1; gate buf0-A readiness
        LDA8(1, 1)
        if (it < 3) { STAGE_H(1, 1, 0, 2 * it + 3) STAGE_H(1, 1, 1, 2 * it + 3) VM4; }
        BAR; MM(bf1, 1, 1) MM(bf0, 1, 0) BAR;
    }
#undef STAGE_H
#undef LDA8
#undef LDB4
#undef MM
#undef VM4
#undef VM0
#undef BAR

    // ---- epilogue (swapped layout): per-speaker sum = 16 VALU adds over
    // (ni,r) + 2 shuffles over lane>>4; speaker = lane&15 within mi-group.
    const int bcol = col0 + wc * 64;
    const int k4 = (lane >> 4) << 2;
#pragma unroll
    for (int mi = 0; mi < 8; ++mi) {
        const int lspk = wr * 128 + mi * 16 + l15;     // local speaker row
        const int gs = row0 + lspk;                    // global speaker
        float t = 0.f, p = 0.f;
#pragma unroll
        for (int ni = 0; ni < 4; ++ni) {
#pragma unroll
            for (int r = 0; r < 4; ++r) {
                const float e = __expf(fmaf(alpha, acc[mi][ni][r], beta));
                t += e;
                if (has_diag) {
                    const int gt = bcol + ni * 16 + k4 + r;   // global test row
                    p += ((gt >> 4) == gs) ? e : 0.f;
                }
            }
        }
        t += __shfl_xor(t, 16, 64);
        t += __shfl_xor(t, 32, 64);
        if (lane < 16) atomicAdd(&rowsum[lspk], t);
        if (has_diag) {
            p += __shfl_xor(p, 16, 64);
            p += __shfl_xor(p, 32, 64);
            if (lane < 16) atomicAdd(&possum[lspk], p);
        }
    }
    __syncthreads();
    if (tid < 256) {
        atomicAdd(&g_row[row0 + tid], rowsum[tid]);
        if (has_diag) atomicAdd(&g_pos[row0 + tid], possum[tid]);
    }
}

// ---------------------------------------------------------------------------
// Kernel 3: loss = mean(log(tot - pos) - log(pos)) — shfl-based, 1 barrier.
// ---------------------------------------------------------------------------
__global__ __launch_bounds__(1024) void finalize_kernel(const float* __restrict__ g_row,
                                                        const float* __restrict__ g_pos,
                                                        float* __restrict__ out) {
    __shared__ float wsum[16];
    const int i = threadIdx.x;
    const int lane = i & 63, wid = i >> 6;
    const float pos = g_pos[i];
    const float neg = g_row[i] - pos;
    float v = logf(fmaxf(neg, 1e-30f)) - logf(fmaxf(pos, 1e-30f));
#pragma unroll
    for (int m = 1; m < 64; m <<= 1) v += __shfl_xor(v, m, 64);
    if (lane == 0) wsum[wid] = v;
    __syncthreads();
    if (i < 64) {
        float s = (i < 16) ? wsum[i] : 0.f;
#pragma unroll
        for (int m = 1; m < 16; m <<= 1) s += __shfl_xor(s, m, 64);
        if (i == 0) out[0] = s * (1.f / 1024.f);
    }
}

extern "C" void kernel_launch(void* const* d_in, const int* in_sizes, int n_in,
                              void* d_out, int out_size, void* d_ws, size_t ws_size,
                              hipStream_t stream) {
    const float* emb = (const float*)d_in[0];
    // d_in[1] = labels (unused; structure fixed by construction)
    const float* alpha_p = (const float*)d_in[2];
    const float* beta_p = (const float*)d_in[3];

    unsigned short* cent = (unsigned short*)d_ws;          // 1024*512 bf16 = 1 MB
    unsigned short* test = cent + (size_t)N_SPK * D;       // 16384*512 bf16 = 16 MB
    float* g_row = (float*)(test + (size_t)N_TEST_ROWS * D);
    float* g_pos = g_row + N_SPK;

    prep_kernel<<<N_SPK + N_TEST_ROWS / 4, 256, 0, stream>>>(emb, cent, test, g_row, g_pos);

    gemm_kernel<<<256, 512, 0, stream>>>(cent, test, alpha_p, beta_p, g_row, g_pos);

    finalize_kernel<<<1, 1024, 0, stream>>>(g_row, g_pos, (float*)d_out);
}